// Round 6
// baseline (199.344 us; speedup 1.0000x reference)
//
#include <hip/hip_runtime.h>
#include <hip/hip_cooperative_groups.h>

namespace cg = cooperative_groups;

#define NPTS 16384

typedef short bf16x8 __attribute__((ext_vector_type(8)));
typedef float f32x16 __attribute__((ext_vector_type(16)));
typedef unsigned short us8v __attribute__((ext_vector_type(8)));

__device__ __forceinline__ unsigned short f2bf(float x) {
  unsigned int u = __float_as_uint(x);
  u = (u + 0x7FFFu + ((u >> 16) & 1u)) >> 16;   // RNE
  return (unsigned short)u;
}
__device__ __forceinline__ float bf2f(unsigned short h) {
  return __uint_as_float(((unsigned int)h) << 16);
}
__device__ __forceinline__ float bflo(unsigned int u) {
  return __uint_as_float(u << 16);
}
__device__ __forceinline__ float bfhi(unsigned int u) {
  return __uint_as_float(u & 0xFFFF0000u);
}

// F features for one B-point (verified encoding, rounds 3-5):
// h0 = {xh,xh,xl,xl, yh,yh,yl,yl} of -2p; h1 = {zh,zh,zl,zl, whi,wmid,wlo,0},
// w = |p|^2 split 3-way.  With G = {xh,xl,xh,xl, yh,yl,yh,yl | zh,zl,zh,zl,
// 1,1,1,0}: F.G = |p|^2 - 2 p.q.
__device__ __forceinline__ void buildF(float x, float y, float z,
                                       us8v& h0, us8v& h1) {
  float t;
  t = -2.0f * x; const unsigned short xh = f2bf(t), xl = f2bf(t - bf2f(xh));
  t = -2.0f * y; const unsigned short yh = f2bf(t), yl = f2bf(t - bf2f(yh));
  t = -2.0f * z; const unsigned short zh = f2bf(t), zl = f2bf(t - bf2f(zh));
  const float w = x * x + y * y + z * z;
  const unsigned short wh = f2bf(w);
  const float w1 = w - bf2f(wh);
  const unsigned short wm = f2bf(w1);
  const unsigned short wl = f2bf(w1 - bf2f(wm));
  h0[0] = xh; h0[1] = xh; h0[2] = xl; h0[3] = xl;
  h0[4] = yh; h0[5] = yh; h0[6] = yl; h0[7] = yl;
  h1[0] = zh; h1[1] = zh; h1[2] = zl; h1[3] = zl;
  h1[4] = wh; h1[5] = wm; h1[6] = wl; h1[7] = 0;
}

// ---------------------------------------------------------------------------
// Single cooperative kernel. grid = 512 = dir(2) x ag(32) x cc(8), 256 thr
// (4 waves), 64 KB LDS -> exactly 2 blocks/CU on 256 CUs (co-resident).
// Phase 1: round-5 fused min (verified, absmax 0.0) -> partial[2*NPTS][8] bf16
// Phase 2: block b min-folds + sums its 64 points -> blocksum[b]
// Phase 3: block 0 sums 512 blocksums -> out[0]
// All reduction topologies fixed => deterministic.
// ---------------------------------------------------------------------------
__global__ __launch_bounds__(256, 2) void chamfer_coop_kernel(
    const float* __restrict__ adv, const float* __restrict__ ori,
    unsigned short* __restrict__ partial /* [2*NPTS][8] bf16 */,
    float* __restrict__ blocksum /* [512] */,
    float* __restrict__ out) {
  __shared__ short lds[2][16384];  // 2 x 32 KB round buffers

  const int bid = blockIdx.x;
  const int dir = bid >> 8;
  const int rr  = bid & 255;
  const int ag  = rr >> 3;   // 0..31 A-group (512 pts)
  const int cc  = rr & 7;    // 0..7  B-chunk (2048 pts)

  const float* __restrict__ A = dir ? ori : adv;
  const float* __restrict__ B = dir ? adv : ori;

  const int tid  = threadIdx.x;  // 0..255
  const int wv   = tid >> 6;
  const int lane = tid & 63;
  const int col  = lane & 31;
  const int half = lane >> 5;

  // ---- issue raw B loads for both rounds (3 x float4 per thread each) ----
  const float* braw = B + (size_t)(cc * 2048) * 3;
  const float4* p40 = (const float4*)(braw + (size_t)(4 * tid) * 3);
  const float4* p41 = (const float4*)(braw + (size_t)(1024 + 4 * tid) * 3);
  const float4 r0a = p40[0], r0b = p40[1], r0c = p40[2];
  const float4 r1a = p41[0], r1b = p41[1], r1c = p41[2];

  // ---- G fragments (MFMA B-operand) for this wave's 4 A-tiles ----
  const unsigned short ONE = 0x3F80;
  bf16x8 g0, g1, g2, g3;
  float q2[4];
  int q[4];
#pragma unroll
  for (int i = 0; i < 4; ++i) {
    const int qi = ag * 512 + wv * 128 + i * 32 + col;
    q[i] = qi;
    const float x = A[qi * 3], y = A[qi * 3 + 1], z = A[qi * 3 + 2];
    q2[i] = x * x + y * y + z * z;
    const unsigned short xh = f2bf(x), xl = f2bf(x - bf2f(xh));
    const unsigned short yh = f2bf(y), yl = f2bf(y - bf2f(yh));
    const unsigned short zh = f2bf(z), zl = f2bf(z - bf2f(zh));
    bf16x8 g;
    g[0] = half ? zh : xh; g[1] = half ? zl : xl;
    g[2] = half ? zh : xh; g[3] = half ? zl : xl;
    g[4] = half ? ONE : yh; g[5] = half ? ONE : yl;
    g[6] = half ? ONE : yh; g[7] = half ? (unsigned short)0 : yl;
    if (i == 0) g0 = g; else if (i == 1) g1 = g;
    else if (i == 2) g2 = g; else g3 = g;
  }

  // LDS slot layout (point-permuted; min over rows is permutation-invariant):
  // half h of point 4t+i at byte h*16384 + i*4096 + t*16.
  auto writeF = [&](int buf, float4 a, float4 b, float4 c) {
    char* base = (char*)&lds[buf][0] + tid * 16;
    us8v h0, h1;
    buildF(a.x, a.y, a.z, h0, h1);
    *(us8v*)(base + 0 * 4096) = h0; *(us8v*)(base + 16384 + 0 * 4096) = h1;
    buildF(a.w, b.x, b.y, h0, h1);
    *(us8v*)(base + 1 * 4096) = h0; *(us8v*)(base + 16384 + 1 * 4096) = h1;
    buildF(b.z, b.w, c.x, h0, h1);
    *(us8v*)(base + 2 * 4096) = h0; *(us8v*)(base + 16384 + 2 * 4096) = h1;
    buildF(c.y, c.z, c.w, h0, h1);
    *(us8v*)(base + 3 * 4096) = h0; *(us8v*)(base + 16384 + 3 * 4096) = h1;
  };

  const f32x16 zacc = {};
  float m0a = 1e30f, m0b = 1e30f, m1a = 1e30f, m1b = 1e30f;
  float m2a = 1e30f, m2b = 1e30f, m3a = 1e30f, m3b = 1e30f;

  auto mfmaRound = [&](int buf) {
    const char* Lb = (const char*)&lds[buf][0] + half * 16384 + col * 16;
    bf16x8 f = *(const bf16x8*)(Lb);
#pragma unroll 4
    for (int gg = 0; gg < 32; ++gg) {
      const bf16x8 fn = *(const bf16x8*)(Lb + ((gg + 1) & 31) * 512);
      const f32x16 a0 = __builtin_amdgcn_mfma_f32_32x32x16_bf16(f, g0, zacc, 0, 0, 0);
      const f32x16 a1 = __builtin_amdgcn_mfma_f32_32x32x16_bf16(f, g1, zacc, 0, 0, 0);
      const f32x16 a2 = __builtin_amdgcn_mfma_f32_32x32x16_bf16(f, g2, zacc, 0, 0, 0);
      const f32x16 a3 = __builtin_amdgcn_mfma_f32_32x32x16_bf16(f, g3, zacc, 0, 0, 0);
      m0a = fminf(fminf(m0a, a0[0]), a0[1]);  m0a = fminf(fminf(m0a, a0[2]), a0[3]);
      m0a = fminf(fminf(m0a, a0[4]), a0[5]);  m0a = fminf(fminf(m0a, a0[6]), a0[7]);
      m0b = fminf(fminf(m0b, a0[8]), a0[9]);  m0b = fminf(fminf(m0b, a0[10]), a0[11]);
      m0b = fminf(fminf(m0b, a0[12]), a0[13]); m0b = fminf(fminf(m0b, a0[14]), a0[15]);
      m1a = fminf(fminf(m1a, a1[0]), a1[1]);  m1a = fminf(fminf(m1a, a1[2]), a1[3]);
      m1a = fminf(fminf(m1a, a1[4]), a1[5]);  m1a = fminf(fminf(m1a, a1[6]), a1[7]);
      m1b = fminf(fminf(m1b, a1[8]), a1[9]);  m1b = fminf(fminf(m1b, a1[10]), a1[11]);
      m1b = fminf(fminf(m1b, a1[12]), a1[13]); m1b = fminf(fminf(m1b, a1[14]), a1[15]);
      m2a = fminf(fminf(m2a, a2[0]), a2[1]);  m2a = fminf(fminf(m2a, a2[2]), a2[3]);
      m2a = fminf(fminf(m2a, a2[4]), a2[5]);  m2a = fminf(fminf(m2a, a2[6]), a2[7]);
      m2b = fminf(fminf(m2b, a2[8]), a2[9]);  m2b = fminf(fminf(m2b, a2[10]), a2[11]);
      m2b = fminf(fminf(m2b, a2[12]), a2[13]); m2b = fminf(fminf(m2b, a2[14]), a2[15]);
      m3a = fminf(fminf(m3a, a3[0]), a3[1]);  m3a = fminf(fminf(m3a, a3[2]), a3[3]);
      m3a = fminf(fminf(m3a, a3[4]), a3[5]);  m3a = fminf(fminf(m3a, a3[6]), a3[7]);
      m3b = fminf(fminf(m3b, a3[8]), a3[9]);  m3b = fminf(fminf(m3b, a3[10]), a3[11]);
      m3b = fminf(fminf(m3b, a3[12]), a3[13]); m3b = fminf(fminf(m3b, a3[14]), a3[15]);
      f = fn;
    }
  };

  // ---- phase 1 pipeline ----
  writeF(0, r0a, r0b, r0c);
  __syncthreads();
  writeF(1, r1a, r1b, r1c);   // overlaps MFMA(buf0)
  mfmaRound(0);
  __syncthreads();
  mfmaRound(1);

  float mc[4];
  mc[0] = fminf(m0a, m0b); mc[1] = fminf(m1a, m1b);
  mc[2] = fminf(m2a, m2b); mc[3] = fminf(m3a, m3b);
#pragma unroll
  for (int i = 0; i < 4; ++i) {
    float m = fminf(mc[i], __shfl_xor(mc[i], 32));
    const float d = fmaxf(m + q2[i], 0.0f);
    if (half == 0)
      partial[(size_t)(dir * NPTS + q[i]) * 8 + cc] = f2bf(d);
  }

  // ---- phase boundary: device-scope visibility + grid barrier ----
  __threadfence();
  cg::this_grid().sync();

  // ---- phase 2: block bid folds + sums its 64 points (wave 0 only) ----
  if (tid < 64) {
    const int pid = bid * 64 + tid;          // 0..32767
    const uint4 v = *(const uint4*)(partial + (size_t)pid * 8);
    float m = fminf(fminf(bflo(v.x), bfhi(v.x)), fminf(bflo(v.y), bfhi(v.y)));
    m = fminf(m, fminf(bflo(v.z), bfhi(v.z)));
    m = fminf(m, fminf(bflo(v.w), bfhi(v.w)));
#pragma unroll
    for (int off = 32; off > 0; off >>= 1) m += __shfl_xor(m, off);
    if (tid == 0) blocksum[bid] = m;
  }

  __threadfence();
  cg::this_grid().sync();

  // ---- phase 3: block 0 sums 512 blocksums ----
  if (bid == 0 && tid < 64) {
    float s = 0.0f;
#pragma unroll
    for (int i = 0; i < 8; ++i) s += blocksum[i * 64 + tid];
#pragma unroll
    for (int off = 32; off > 0; off >>= 1) s += __shfl_xor(s, off);
    if (tid == 0) out[0] = s * (1.0f / (float)NPTS);  // LOSS_WEIGHT = 1
  }
}

// ---------------------------------------------------------------------------
// Fallback (ws too small): round-5 two-dispatch path.
// ---------------------------------------------------------------------------
__global__ __launch_bounds__(256, 2) void chamfer_fused_kernel(
    const float* __restrict__ adv, const float* __restrict__ ori,
    unsigned short* __restrict__ partial) {
  __shared__ short lds[2][16384];
  const int bid = blockIdx.x;
  const int dir = bid >> 8;
  const int rr  = bid & 255;
  const int ag  = rr >> 3;
  const int cc  = rr & 7;
  const float* __restrict__ A = dir ? ori : adv;
  const float* __restrict__ B = dir ? adv : ori;
  const int tid  = threadIdx.x;
  const int wv   = tid >> 6;
  const int lane = tid & 63;
  const int col  = lane & 31;
  const int half = lane >> 5;
  const float* braw = B + (size_t)(cc * 2048) * 3;
  const float4* p40 = (const float4*)(braw + (size_t)(4 * tid) * 3);
  const float4* p41 = (const float4*)(braw + (size_t)(1024 + 4 * tid) * 3);
  const float4 r0a = p40[0], r0b = p40[1], r0c = p40[2];
  const float4 r1a = p41[0], r1b = p41[1], r1c = p41[2];
  const unsigned short ONE = 0x3F80;
  bf16x8 g0, g1, g2, g3;
  float q2[4];
  int q[4];
#pragma unroll
  for (int i = 0; i < 4; ++i) {
    const int qi = ag * 512 + wv * 128 + i * 32 + col;
    q[i] = qi;
    const float x = A[qi * 3], y = A[qi * 3 + 1], z = A[qi * 3 + 2];
    q2[i] = x * x + y * y + z * z;
    const unsigned short xh = f2bf(x), xl = f2bf(x - bf2f(xh));
    const unsigned short yh = f2bf(y), yl = f2bf(y - bf2f(yh));
    const unsigned short zh = f2bf(z), zl = f2bf(z - bf2f(zh));
    bf16x8 g;
    g[0] = half ? zh : xh; g[1] = half ? zl : xl;
    g[2] = half ? zh : xh; g[3] = half ? zl : xl;
    g[4] = half ? ONE : yh; g[5] = half ? ONE : yl;
    g[6] = half ? ONE : yh; g[7] = half ? (unsigned short)0 : yl;
    if (i == 0) g0 = g; else if (i == 1) g1 = g;
    else if (i == 2) g2 = g; else g3 = g;
  }
  auto writeF = [&](int buf, float4 a, float4 b, float4 c) {
    char* base = (char*)&lds[buf][0] + tid * 16;
    us8v h0, h1;
    buildF(a.x, a.y, a.z, h0, h1);
    *(us8v*)(base + 0 * 4096) = h0; *(us8v*)(base + 16384 + 0 * 4096) = h1;
    buildF(a.w, b.x, b.y, h0, h1);
    *(us8v*)(base + 1 * 4096) = h0; *(us8v*)(base + 16384 + 1 * 4096) = h1;
    buildF(b.z, b.w, c.x, h0, h1);
    *(us8v*)(base + 2 * 4096) = h0; *(us8v*)(base + 16384 + 2 * 4096) = h1;
    buildF(c.y, c.z, c.w, h0, h1);
    *(us8v*)(base + 3 * 4096) = h0; *(us8v*)(base + 16384 + 3 * 4096) = h1;
  };
  const f32x16 zacc = {};
  float m0a = 1e30f, m0b = 1e30f, m1a = 1e30f, m1b = 1e30f;
  float m2a = 1e30f, m2b = 1e30f, m3a = 1e30f, m3b = 1e30f;
  auto mfmaRound = [&](int buf) {
    const char* Lb = (const char*)&lds[buf][0] + half * 16384 + col * 16;
    bf16x8 f = *(const bf16x8*)(Lb);
#pragma unroll 4
    for (int gg = 0; gg < 32; ++gg) {
      const bf16x8 fn = *(const bf16x8*)(Lb + ((gg + 1) & 31) * 512);
      const f32x16 a0 = __builtin_amdgcn_mfma_f32_32x32x16_bf16(f, g0, zacc, 0, 0, 0);
      const f32x16 a1 = __builtin_amdgcn_mfma_f32_32x32x16_bf16(f, g1, zacc, 0, 0, 0);
      const f32x16 a2 = __builtin_amdgcn_mfma_f32_32x32x16_bf16(f, g2, zacc, 0, 0, 0);
      const f32x16 a3 = __builtin_amdgcn_mfma_f32_32x32x16_bf16(f, g3, zacc, 0, 0, 0);
      m0a = fminf(fminf(m0a, a0[0]), a0[1]);  m0a = fminf(fminf(m0a, a0[2]), a0[3]);
      m0a = fminf(fminf(m0a, a0[4]), a0[5]);  m0a = fminf(fminf(m0a, a0[6]), a0[7]);
      m0b = fminf(fminf(m0b, a0[8]), a0[9]);  m0b = fminf(fminf(m0b, a0[10]), a0[11]);
      m0b = fminf(fminf(m0b, a0[12]), a0[13]); m0b = fminf(fminf(m0b, a0[14]), a0[15]);
      m1a = fminf(fminf(m1a, a1[0]), a1[1]);  m1a = fminf(fminf(m1a, a1[2]), a1[3]);
      m1a = fminf(fminf(m1a, a1[4]), a1[5]);  m1a = fminf(fminf(m1a, a1[6]), a1[7]);
      m1b = fminf(fminf(m1b, a1[8]), a1[9]);  m1b = fminf(fminf(m1b, a1[10]), a1[11]);
      m1b = fminf(fminf(m1b, a1[12]), a1[13]); m1b = fminf(fminf(m1b, a1[14]), a1[15]);
      m2a = fminf(fminf(m2a, a2[0]), a2[1]);  m2a = fminf(fminf(m2a, a2[2]), a2[3]);
      m2a = fminf(fminf(m2a, a2[4]), a2[5]);  m2a = fminf(fminf(m2a, a2[6]), a2[7]);
      m2b = fminf(fminf(m2b, a2[8]), a2[9]);  m2b = fminf(fminf(m2b, a2[10]), a2[11]);
      m2b = fminf(fminf(m2b, a2[12]), a2[13]); m2b = fminf(fminf(m2b, a2[14]), a2[15]);
      m3a = fminf(fminf(m3a, a3[0]), a3[1]);  m3a = fminf(fminf(m3a, a3[2]), a3[3]);
      m3a = fminf(fminf(m3a, a3[4]), a3[5]);  m3a = fminf(fminf(m3a, a3[6]), a3[7]);
      m3b = fminf(fminf(m3b, a3[8]), a3[9]);  m3b = fminf(fminf(m3b, a3[10]), a3[11]);
      m3b = fminf(fminf(m3b, a3[12]), a3[13]); m3b = fminf(fminf(m3b, a3[14]), a3[15]);
      f = fn;
    }
  };
  writeF(0, r0a, r0b, r0c);
  __syncthreads();
  writeF(1, r1a, r1b, r1c);
  mfmaRound(0);
  __syncthreads();
  mfmaRound(1);
  float mc[4];
  mc[0] = fminf(m0a, m0b); mc[1] = fminf(m1a, m1b);
  mc[2] = fminf(m2a, m2b); mc[3] = fminf(m3a, m3b);
#pragma unroll
  for (int i = 0; i < 4; ++i) {
    float m = fminf(mc[i], __shfl_xor(mc[i], 32));
    const float d = fmaxf(m + q2[i], 0.0f);
    if (half == 0)
      partial[(size_t)(dir * NPTS + q[i]) * 8 + cc] = f2bf(d);
  }
}

__global__ __launch_bounds__(1024) void chamfer_reduce_bf16_kernel(
    const unsigned short* __restrict__ partial, float* __restrict__ out) {
  __shared__ float red[1024];
  const int tid = threadIdx.x;
  const uint4* p4 = (const uint4*)partial;
  float s = 0.0f;
#pragma unroll 8
  for (int it = 0; it < 32; ++it) {
    const uint4 v = p4[it * 1024 + tid];
    float m = fminf(fminf(bflo(v.x), bfhi(v.x)), fminf(bflo(v.y), bfhi(v.y)));
    m = fminf(m, fminf(bflo(v.z), bfhi(v.z)));
    m = fminf(m, fminf(bflo(v.w), bfhi(v.w)));
    s += m;
  }
  red[tid] = s;
  __syncthreads();
  for (int off = 512; off > 0; off >>= 1) {
    if (tid < off) red[tid] += red[tid + off];
    __syncthreads();
  }
  if (tid == 0) out[0] = red[0] * (1.0f / (float)NPTS);
}

extern "C" void kernel_launch(void* const* d_in, const int* in_sizes, int n_in,
                              void* d_out, int out_size, void* d_ws, size_t ws_size,
                              hipStream_t stream) {
  const float* adv = (const float*)d_in[0];
  const float* ori = (const float*)d_in[1];
  float* out = (float*)d_out;

  const size_t partial_bytes = (size_t)2 * NPTS * 8 * sizeof(unsigned short);  // 512 KB
  const size_t need = partial_bytes + 512 * sizeof(float);

  if (ws_size >= need) {
    unsigned short* partial = (unsigned short*)d_ws;
    float* blocksum = (float*)((char*)d_ws + partial_bytes);
    void* args[] = {(void*)&adv, (void*)&ori, (void*)&partial,
                    (void*)&blocksum, (void*)&out};
    hipLaunchCooperativeKernel((void*)chamfer_coop_kernel, dim3(512), dim3(256),
                               args, 0, stream);
  } else if (ws_size >= partial_bytes) {
    unsigned short* partial = (unsigned short*)d_ws;
    chamfer_fused_kernel<<<512, 256, 0, stream>>>(adv, ori, partial);
    chamfer_reduce_bf16_kernel<<<1, 1024, 0, stream>>>(partial, out);
  }
}

// Round 7
// 29.653 us; speedup vs baseline: 6.7226x; 6.7226x over previous
//
#include <hip/hip_runtime.h>

#define NPTS 16384

typedef short bf16x8 __attribute__((ext_vector_type(8)));
typedef float f32x16 __attribute__((ext_vector_type(16)));
typedef unsigned short us8v __attribute__((ext_vector_type(8)));

__device__ __forceinline__ unsigned short f2bf(float x) {
  unsigned int u = __float_as_uint(x);
  u = (u + 0x7FFFu + ((u >> 16) & 1u)) >> 16;   // RNE
  return (unsigned short)u;
}
__device__ __forceinline__ float bf2f(unsigned short h) {
  return __uint_as_float(((unsigned int)h) << 16);
}

// ---------------------------------------------------------------------------
// Prepack (verified round 3/4): per point p, A-operand features F_p[16] bf16:
// per coord c: {hi(-2p_c), hi, lo, lo}; ch12-14 = 3-way split of |p|^2;
// ch15 = 0.  S[p][q] = F_p . G_q = |p|^2 - 2 p.q; d = S + |q|^2.
// Tile-interleaved layout = exact 32x32x16 A-frag order, so staging and
// ds_read_b128 are linear.  Also initializes minbuf (replaces fill dispatch).
// ---------------------------------------------------------------------------
__global__ __launch_bounds__(256) void prepack_kernel(
    const float* __restrict__ adv, const float* __restrict__ ori,
    unsigned short* __restrict__ Fall, unsigned int* __restrict__ minbuf) {
  const int id = blockIdx.x * 256 + threadIdx.x;  // 0..32767
  minbuf[id] = 0x7F7F7F7Fu;  // > any finite non-negative float bit pattern

  const int s = id >> 14;
  const int p = id & (NPTS - 1);
  const float* P = s ? ori : adv;
  const float x = P[p * 3 + 0], y = P[p * 3 + 1], z = P[p * 3 + 2];

  unsigned short o[16];
  const float co[3] = {x, y, z};
#pragma unroll
  for (int c = 0; c < 3; ++c) {
    const float t = -2.0f * co[c];
    const unsigned short hi = f2bf(t);
    const unsigned short lo = f2bf(t - bf2f(hi));
    o[4 * c + 0] = hi; o[4 * c + 1] = hi;
    o[4 * c + 2] = lo; o[4 * c + 3] = lo;
  }
  const float w = x * x + y * y + z * z;
  const unsigned short whi = f2bf(w);
  const float w1 = w - bf2f(whi);
  const unsigned short wmid = f2bf(w1);
  const unsigned short wlo = f2bf(w1 - bf2f(wmid));
  o[12] = whi; o[13] = wmid; o[14] = wlo; o[15] = 0;

  unsigned short* base = Fall + (size_t)s * (NPTS * 16) + (p >> 5) * 512 + (p & 31) * 8;
  us8v h0, h1;
#pragma unroll
  for (int i = 0; i < 8; ++i) { h0[i] = o[i]; h1[i] = o[8 + i]; }
  *(us8v*)(base) = h0;          // half 0 (ch 0-7)
  *(us8v*)(base + 256) = h1;    // half 1 (ch 8-15)
}

// ---------------------------------------------------------------------------
// Main: 256 blocks x 512 thr (8 waves), 2 blocks/CU (4 waves/SIMD).
// bid -> {dir, A-group(512 pts), B-chunk(4096 pts)}.  Wave: 2 A-tiles
// (G-frags in-register).  Inner loop FULLY UNROLLED over 32 tiles with
// compile-time ds offsets; min-fold as a depth-3 min3 tree (8 min3/MFMA,
// loop-carried chain length 1/iter).  B staged via global_load_lds,
// double-buffered 2x32KB.
// ---------------------------------------------------------------------------
__global__ __launch_bounds__(512, 4) void chamfer_mfma_kernel(
    const float* __restrict__ adv, const float* __restrict__ ori,
    const unsigned short* __restrict__ Fall,
    unsigned int* __restrict__ minbuf) {
  __shared__ short lds[2][16384];  // 2 x 32 KB

  const int bid = blockIdx.x;
  const int dir = bid >> 7;
  const int rr = bid & 127;
  const int ag = rr >> 2;  // 0..31  A-group
  const int cc = rr & 3;   // 0..3   B-chunk

  const float* __restrict__ A = dir ? ori : adv;
  const unsigned short* __restrict__ F = Fall + (size_t)(1 - dir) * (NPTS * 16);

  const int w = threadIdx.x >> 6;
  const int lane = threadIdx.x & 63;
  const int col = lane & 31;
  const int half = lane >> 5;

  // ---- G fragments (MFMA B-operand) for this wave's 2 A-tiles ----
  const int at0 = ag * 16 + w * 2;
  const int q0 = at0 * 32 + col;
  const int q1 = q0 + 32;
  const float x0 = A[q0 * 3], y0 = A[q0 * 3 + 1], z0 = A[q0 * 3 + 2];
  const float x1 = A[q1 * 3], y1 = A[q1 * 3 + 1], z1 = A[q1 * 3 + 2];

  const unsigned short ONE = 0x3F80;
  bf16x8 g0, g1;
  {
    unsigned short xh = f2bf(x0), xl = f2bf(x0 - bf2f(xh));
    unsigned short yh = f2bf(y0), yl = f2bf(y0 - bf2f(yh));
    unsigned short zh = f2bf(z0), zl = f2bf(z0 - bf2f(zh));
    g0[0] = half ? zh : xh; g0[1] = half ? zl : xl;
    g0[2] = half ? zh : xh; g0[3] = half ? zl : xl;
    g0[4] = half ? ONE : yh; g0[5] = half ? ONE : yl;
    g0[6] = half ? ONE : yh; g0[7] = half ? (unsigned short)0 : yl;
  }
  {
    unsigned short xh = f2bf(x1), xl = f2bf(x1 - bf2f(xh));
    unsigned short yh = f2bf(y1), yl = f2bf(y1 - bf2f(yh));
    unsigned short zh = f2bf(z1), zl = f2bf(z1 - bf2f(zh));
    g1[0] = half ? zh : xh; g1[1] = half ? zl : xl;
    g1[2] = half ? zh : xh; g1[3] = half ? zl : xl;
    g1[4] = half ? ONE : yh; g1[5] = half ? ONE : yl;
    g1[6] = half ? ONE : yh; g1[7] = half ? (unsigned short)0 : yl;
  }

  const unsigned short* Fc = F + cc * (4096 * 16);  // chunk base

  auto stage = [&](int r, int buf) {
    const char* src = (const char*)(Fc + r * 16384);
#pragma unroll
    for (int s = 0; s < 4; ++s) {
      const int seg = w * 4 + s;
      __builtin_amdgcn_global_load_lds(
          (const __attribute__((address_space(1))) void*)(src + seg * 1024 + lane * 16),
          (__attribute__((address_space(3))) void*)((char*)&lds[buf][0] + seg * 1024),
          16, 0, 0);
    }
  };

  const f32x16 zacc = {};
  float m0 = 1e30f, m1 = 1e30f;

  stage(0, 0);
  for (int r = 0; r < 4; ++r) {
    __syncthreads();  // vmcnt(0) drain before barrier -> buf ready
    if (r < 3) stage(r + 1, (r + 1) & 1);
    // lane offset: col*16 + half*512 == lane*16 bytes (frag layout)
    const char* Lb = (const char*)&lds[r & 1][0] + lane * 16;

#pragma unroll
    for (int t = 0; t < 32; ++t) {
      const bf16x8 f = *(const bf16x8*)(Lb + t * 1024);  // imm-offset ds_read_b128
      const f32x16 a0 = __builtin_amdgcn_mfma_f32_32x32x16_bf16(f, g0, zacc, 0, 0, 0);
      const f32x16 a1 = __builtin_amdgcn_mfma_f32_32x32x16_bf16(f, g1, zacc, 0, 0, 0);
      // depth-3 min3 tree, 8 min3 per MFMA, independent leaves
      {
        const float u0 = fminf(fminf(a0[0], a0[1]), a0[2]);
        const float u1 = fminf(fminf(a0[3], a0[4]), a0[5]);
        const float u2 = fminf(fminf(a0[6], a0[7]), a0[8]);
        const float u3 = fminf(fminf(a0[9], a0[10]), a0[11]);
        const float u4 = fminf(fminf(a0[12], a0[13]), a0[14]);
        const float v0 = fminf(fminf(u0, u1), u2);
        const float v1 = fminf(fminf(u3, u4), a0[15]);
        m0 = fminf(fminf(m0, v0), v1);
      }
      {
        const float u0 = fminf(fminf(a1[0], a1[1]), a1[2]);
        const float u1 = fminf(fminf(a1[3], a1[4]), a1[5]);
        const float u2 = fminf(fminf(a1[6], a1[7]), a1[8]);
        const float u3 = fminf(fminf(a1[9], a1[10]), a1[11]);
        const float u4 = fminf(fminf(a1[12], a1[13]), a1[14]);
        const float v0 = fminf(fminf(u0, u1), u2);
        const float v1 = fminf(fminf(u3, u4), a1[15]);
        m1 = fminf(fminf(m1, v0), v1);
      }
    }
  }

  // ---- epilogue: fold halves (rows in lanes^32), add |q|^2 ----
  float mc0 = fminf(m0, __shfl_xor(m0, 32));
  float mc1 = fminf(m1, __shfl_xor(m1, 32));
  const float d0 = fmaxf(mc0 + (x0 * x0 + y0 * y0 + z0 * z0), 0.0f);
  const float d1 = fmaxf(mc1 + (x1 * x1 + y1 * y1 + z1 * z1), 0.0f);
  if (half == 0) {
    atomicMin(&minbuf[dir * NPTS + q0], __float_as_uint(d0));
    atomicMin(&minbuf[dir * NPTS + q1], __float_as_uint(d1));
  }
}

// Single block: sum all 2*NPTS per-point mins (uint4-vectorized), /NPTS.
__global__ __launch_bounds__(1024) void chamfer_reduce_kernel(
    const unsigned int* __restrict__ minbuf, float* __restrict__ out) {
  __shared__ float red[1024];
  const int tid = threadIdx.x;
  const uint4* mb4 = (const uint4*)minbuf;
  float s = 0.0f;
#pragma unroll
  for (int it = 0; it < 8; ++it) {
    const uint4 v = mb4[it * 1024 + tid];
    s += __uint_as_float(v.x) + __uint_as_float(v.y) +
         __uint_as_float(v.z) + __uint_as_float(v.w);
  }
  red[tid] = s;
  __syncthreads();
  for (int off = 512; off > 0; off >>= 1) {
    if (tid < off) red[tid] += red[tid + off];
    __syncthreads();
  }
  if (tid == 0) out[0] = red[0] * (1.0f / (float)NPTS);  // LOSS_WEIGHT = 1
}

// ---------------------------------------------------------------------------
// Fallback (ws too small): round-2 VALU kernel.
// ---------------------------------------------------------------------------
__global__ __launch_bounds__(256) void chamfer_valu_kernel(
    const float* __restrict__ adv, const float* __restrict__ ori,
    unsigned int* __restrict__ minbuf) {
  __shared__ float4 bt[512];
  const int bx = blockIdx.x;
  const int c = bx & 31;
  const int t = bx >> 5;
  const int dir = t & 1;
  const int ab = t >> 1;
  const float* __restrict__ A = dir ? ori : adv;
  const float* __restrict__ B = dir ? adv : ori;
  const int tid = threadIdx.x;
  for (int j = tid; j < 512; j += 256) {
    const float* bp = B + (size_t)(c * 512 + j) * 3;
    const float x = bp[0], y = bp[1], z = bp[2];
    bt[j] = make_float4(x, y, z, 0.5f * (x * x + y * y + z * z));
  }
  float nax[8], nay[8], naz[8], a2[8], mn[8];
#pragma unroll
  for (int k = 0; k < 8; ++k) {
    const int idx = ab * 2048 + k * 256 + tid;
    const float* ap = A + (size_t)idx * 3;
    const float x = ap[0], y = ap[1], z = ap[2];
    nax[k] = -x; nay[k] = -y; naz[k] = -z;
    a2[k] = x * x + y * y + z * z;
    mn[k] = 1e30f;
  }
  __syncthreads();
#pragma unroll 4
  for (int j = 0; j < 512; j += 2) {
    const float4 b0 = bt[j];
    const float4 b1 = bt[j + 1];
#pragma unroll
    for (int k = 0; k < 8; ++k) {
      const float t0 = fmaf(nax[k], b0.x, fmaf(nay[k], b0.y, fmaf(naz[k], b0.z, b0.w)));
      const float t1 = fmaf(nax[k], b1.x, fmaf(nay[k], b1.y, fmaf(naz[k], b1.z, b1.w)));
      mn[k] = fminf(fminf(mn[k], t0), t1);
    }
  }
#pragma unroll
  for (int k = 0; k < 8; ++k) {
    const int idx = ab * 2048 + k * 256 + tid;
    const float v = fmaf(2.0f, mn[k], a2[k]);
    atomicMin(&minbuf[dir * NPTS + idx], __float_as_uint(v));
  }
}

extern "C" void kernel_launch(void* const* d_in, const int* in_sizes, int n_in,
                              void* d_out, int out_size, void* d_ws, size_t ws_size,
                              hipStream_t stream) {
  const float* adv = (const float*)d_in[0];
  const float* ori = (const float*)d_in[1];
  float* out = (float*)d_out;
  unsigned int* minbuf = (unsigned int*)d_ws;

  const size_t need = 131072 + (size_t)2 * NPTS * 16 * sizeof(unsigned short);  // 128K + 1M

  if (ws_size >= need) {
    unsigned short* Fall = (unsigned short*)((char*)d_ws + 131072);
    prepack_kernel<<<128, 256, 0, stream>>>(adv, ori, Fall, minbuf);  // also inits minbuf
    chamfer_mfma_kernel<<<256, 512, 0, stream>>>(adv, ori, Fall, minbuf);
  } else {
    hipMemsetAsync(minbuf, 0x7F, (size_t)(2 * NPTS) * sizeof(unsigned int), stream);
    chamfer_valu_kernel<<<1024, 256, 0, stream>>>(adv, ori, minbuf);
  }
  chamfer_reduce_kernel<<<1, 1024, 0, stream>>>(minbuf, out);
}